// Round 1
// baseline (2991.286 us; speedup 1.0000x reference)
//
#include <hip/hip_runtime.h>
#include <hip/hip_bf16.h>

// Fused dual GEMM: h0 = act(x) @ w0 + b0 ; h1 = act(x) @ w1 + b1
// act = relu if relu_in else identity. x tile staged in LDS, weights via L1/L2.
template<int DIN, int DOUT, int BM>
__global__ void gemm2_kernel(const float* __restrict__ x,
                             const float* __restrict__ w0, const float* __restrict__ b0,
                             const float* __restrict__ w1, const float* __restrict__ b1,
                             float* __restrict__ h0, float* __restrict__ h1,
                             int N, int relu_in)
{
    __shared__ float xs[BM * DIN];
    const int row0 = blockIdx.x * BM;
    const int tid  = threadIdx.x;
    const int nt   = blockDim.x;

    // stage BM x DIN tile of x into LDS (coalesced), fold relu
    for (int i = tid; i < BM * DIN; i += nt) {
        int r = i / DIN;
        int k = i - r * DIN;
        int gr = row0 + r;
        float v = (gr < N) ? x[(size_t)gr * DIN + k] : 0.f;
        if (relu_in) v = fmaxf(v, 0.f);
        xs[i] = v;
    }
    __syncthreads();

    const int c = tid;
    if (c >= DOUT) return;

    float acc0[BM], acc1[BM];
    const float bb0 = b0[c], bb1 = b1[c];
#pragma unroll
    for (int r = 0; r < BM; ++r) { acc0[r] = bb0; acc1[r] = bb1; }

    for (int k = 0; k < DIN; k += 4) {
        const float w00 = w0[(k + 0) * DOUT + c];
        const float w01 = w0[(k + 1) * DOUT + c];
        const float w02 = w0[(k + 2) * DOUT + c];
        const float w03 = w0[(k + 3) * DOUT + c];
        const float w10 = w1[(k + 0) * DOUT + c];
        const float w11 = w1[(k + 1) * DOUT + c];
        const float w12 = w1[(k + 2) * DOUT + c];
        const float w13 = w1[(k + 3) * DOUT + c];
#pragma unroll
        for (int r = 0; r < BM; ++r) {
            const float4 xq = *reinterpret_cast<const float4*>(&xs[r * DIN + k]); // broadcast b128
            acc0[r] = fmaf(xq.x, w00, acc0[r]);
            acc0[r] = fmaf(xq.y, w01, acc0[r]);
            acc0[r] = fmaf(xq.z, w02, acc0[r]);
            acc0[r] = fmaf(xq.w, w03, acc0[r]);
            acc1[r] = fmaf(xq.x, w10, acc1[r]);
            acc1[r] = fmaf(xq.y, w11, acc1[r]);
            acc1[r] = fmaf(xq.z, w12, acc1[r]);
            acc1[r] = fmaf(xq.w, w13, acc1[r]);
        }
    }

#pragma unroll
    for (int r = 0; r < BM; ++r) {
        int gr = row0 + r;
        if (gr < N) {
            h0[(size_t)gr * DOUT + c] = acc0[r];
            h1[(size_t)gr * DOUT + c] = acc1[r];
        }
    }
}

// Layer 3 special case: DIN=64, DOUT=3. One row per thread, weights in LDS.
__global__ void gemm2_small_kernel(const float* __restrict__ x,
                                   const float* __restrict__ w0, const float* __restrict__ b0,
                                   const float* __restrict__ w1, const float* __restrict__ b1,
                                   float* __restrict__ h0, float* __restrict__ h1,
                                   int N, int relu_in)
{
    __shared__ float ws0[64 * 3];
    __shared__ float ws1[64 * 3];
    const int tid = threadIdx.x;
    if (tid < 192) { ws0[tid] = w0[tid]; ws1[tid] = w1[tid]; }
    __syncthreads();

    const int r = blockIdx.x * blockDim.x + tid;
    if (r >= N) return;

    float acc0[3] = { b0[0], b0[1], b0[2] };
    float acc1[3] = { b1[0], b1[1], b1[2] };

    const float4* x4 = reinterpret_cast<const float4*>(x + (size_t)r * 64);
#pragma unroll
    for (int kk = 0; kk < 16; ++kk) {
        float4 xq = x4[kk];
        float xv[4] = { xq.x, xq.y, xq.z, xq.w };
        if (relu_in) {
#pragma unroll
            for (int j = 0; j < 4; ++j) xv[j] = fmaxf(xv[j], 0.f);
        }
#pragma unroll
        for (int j = 0; j < 4; ++j) {
            const int k = kk * 4 + j;
#pragma unroll
            for (int c = 0; c < 3; ++c) {
                acc0[c] = fmaf(xv[j], ws0[k * 3 + c], acc0[c]);
                acc1[c] = fmaf(xv[j], ws1[k * 3 + c], acc1[c]);
            }
        }
    }
    h0[(size_t)r * 3 + 0] = acc0[0];
    h0[(size_t)r * 3 + 1] = acc0[1];
    h0[(size_t)r * 3 + 2] = acc0[2];
    h1[(size_t)r * 3 + 0] = acc1[0];
    h1[(size_t)r * 3 + 1] = acc1[1];
    h1[(size_t)r * 3 + 2] = acc1[2];
}

// out[src] += h1[dst]; out[dst] += h1[src] for every edge (atomic fp32).
template<int DOUT>
__global__ void scatter_kernel(const int* __restrict__ edges,
                               const float* __restrict__ h1,
                               float* __restrict__ out,
                               int n_edges)
{
    const unsigned total  = (unsigned)n_edges * (unsigned)DOUT;
    const unsigned stride = gridDim.x * blockDim.x;
    for (unsigned idx = blockIdx.x * blockDim.x + threadIdx.x; idx < total; idx += stride) {
        const unsigned e = idx / DOUT;          // compile-time DOUT -> magic mul
        const unsigned c = idx - e * DOUT;
        const int s = edges[2 * e + 0];
        const int d = edges[2 * e + 1];
        const float vd = h1[(size_t)d * DOUT + c];
        const float vs = h1[(size_t)s * DOUT + c];
        atomicAdd(&out[(size_t)s * DOUT + c], vd);
        atomicAdd(&out[(size_t)d * DOUT + c], vs);
    }
}

extern "C" void kernel_launch(void* const* d_in, const int* in_sizes, int n_in,
                              void* d_out, int out_size, void* d_ws, size_t ws_size,
                              hipStream_t stream)
{
    const float* feat  = (const float*)d_in[0];
    const int*   edges = (const int*)d_in[1];
    const float *W0[4], *B0[4], *W1[4], *B1[4];
    for (int i = 0; i < 4; ++i) {
        W0[i] = (const float*)d_in[2 + i * 4 + 0];
        B0[i] = (const float*)d_in[2 + i * 4 + 1];
        W1[i] = (const float*)d_in[2 + i * 4 + 2];
        B1[i] = (const float*)d_in[2 + i * 4 + 3];
    }
    const int N  = in_sizes[0] / 256;
    const int nE = in_sizes[1] / 2;

    float* out  = (float*)d_out;
    float* bufA = (float*)d_ws;                  // N*192 f32
    float* bufB = bufA + (size_t)N * 192;        // N*192 f32
    float* bufC = bufB + (size_t)N * 192;        // N*128 f32
    // total ws use: N*512*4 B ~= 410 MB

    constexpr int BM = 16;
    const int gGemm    = (N + BM - 1) / BM;
    const int gScatter = 4096;

    // layer 0: 256 -> 192 (input = features, no relu on input)
    gemm2_kernel<256, 192, BM><<<gGemm, 192, 0, stream>>>(feat, W0[0], B0[0], W1[0], B1[0], bufA, bufB, N, 0);
    scatter_kernel<192><<<gScatter, 256, 0, stream>>>(edges, bufB, bufA, nE);

    // layer 1: 192 -> 128 (relu folded into x load)
    gemm2_kernel<192, 128, BM><<<gGemm, 128, 0, stream>>>(bufA, W0[1], B0[1], W1[1], B1[1], bufC, bufB, N, 1);
    scatter_kernel<128><<<gScatter, 256, 0, stream>>>(edges, bufB, bufC, nE);

    // layer 2: 128 -> 64
    gemm2_kernel<128, 64, BM><<<gGemm, 64, 0, stream>>>(bufC, W0[2], B0[2], W1[2], B1[2], bufA, bufB, N, 1);
    scatter_kernel<64><<<gScatter, 256, 0, stream>>>(edges, bufB, bufA, nE);

    // layer 3: 64 -> 3, h0 straight into d_out, then scatter-add into d_out
    gemm2_small_kernel<<<(N + 255) / 256, 256, 0, stream>>>(bufA, W0[3], B0[3], W1[3], B1[3], out, bufB, N, 1);
    scatter_kernel<3><<<gScatter, 256, 0, stream>>>(edges, bufB, out, nE);
}

// Round 3
// 2016.098 us; speedup vs baseline: 1.4837x; 1.4837x over previous
//
#include <hip/hip_runtime.h>
#include <hip/hip_bf16.h>

#define ADJ_CAP 40

// ---------------- GEMMs (unchanged from R1) ----------------
template<int DIN, int DOUT, int BM>
__global__ void gemm2_kernel(const float* __restrict__ x,
                             const float* __restrict__ w0, const float* __restrict__ b0,
                             const float* __restrict__ w1, const float* __restrict__ b1,
                             float* __restrict__ h0, float* __restrict__ h1,
                             int N, int relu_in)
{
    __shared__ float xs[BM * DIN];
    const int row0 = blockIdx.x * BM;
    const int tid  = threadIdx.x;
    const int nt   = blockDim.x;

    for (int i = tid; i < BM * DIN; i += nt) {
        int r = i / DIN;
        int k = i - r * DIN;
        int gr = row0 + r;
        float v = (gr < N) ? x[(size_t)gr * DIN + k] : 0.f;
        if (relu_in) v = fmaxf(v, 0.f);
        xs[i] = v;
    }
    __syncthreads();

    const int c = tid;
    if (c >= DOUT) return;

    float acc0[BM], acc1[BM];
    const float bb0 = b0[c], bb1 = b1[c];
#pragma unroll
    for (int r = 0; r < BM; ++r) { acc0[r] = bb0; acc1[r] = bb1; }

    for (int k = 0; k < DIN; k += 4) {
        const float w00 = w0[(k + 0) * DOUT + c];
        const float w01 = w0[(k + 1) * DOUT + c];
        const float w02 = w0[(k + 2) * DOUT + c];
        const float w03 = w0[(k + 3) * DOUT + c];
        const float w10 = w1[(k + 0) * DOUT + c];
        const float w11 = w1[(k + 1) * DOUT + c];
        const float w12 = w1[(k + 2) * DOUT + c];
        const float w13 = w1[(k + 3) * DOUT + c];
#pragma unroll
        for (int r = 0; r < BM; ++r) {
            const float4 xq = *reinterpret_cast<const float4*>(&xs[r * DIN + k]);
            acc0[r] = fmaf(xq.x, w00, acc0[r]);
            acc0[r] = fmaf(xq.y, w01, acc0[r]);
            acc0[r] = fmaf(xq.z, w02, acc0[r]);
            acc0[r] = fmaf(xq.w, w03, acc0[r]);
            acc1[r] = fmaf(xq.x, w10, acc1[r]);
            acc1[r] = fmaf(xq.y, w11, acc1[r]);
            acc1[r] = fmaf(xq.z, w12, acc1[r]);
            acc1[r] = fmaf(xq.w, w13, acc1[r]);
        }
    }

#pragma unroll
    for (int r = 0; r < BM; ++r) {
        int gr = row0 + r;
        if (gr < N) {
            h0[(size_t)gr * DOUT + c] = acc0[r];
            h1[(size_t)gr * DOUT + c] = acc1[r];
        }
    }
}

__global__ void gemm2_small_kernel(const float* __restrict__ x,
                                   const float* __restrict__ w0, const float* __restrict__ b0,
                                   const float* __restrict__ w1, const float* __restrict__ b1,
                                   float* __restrict__ h0, float* __restrict__ h1,
                                   int N, int relu_in)
{
    __shared__ float ws0[64 * 3];
    __shared__ float ws1[64 * 3];
    const int tid = threadIdx.x;
    if (tid < 192) { ws0[tid] = w0[tid]; ws1[tid] = w1[tid]; }
    __syncthreads();

    const int r = blockIdx.x * blockDim.x + tid;
    if (r >= N) return;

    float acc0[3] = { b0[0], b0[1], b0[2] };
    float acc1[3] = { b1[0], b1[1], b1[2] };

    const float4* x4 = reinterpret_cast<const float4*>(x + (size_t)r * 64);
#pragma unroll
    for (int kk = 0; kk < 16; ++kk) {
        float4 xq = x4[kk];
        float xv[4] = { xq.x, xq.y, xq.z, xq.w };
        if (relu_in) {
#pragma unroll
            for (int j = 0; j < 4; ++j) xv[j] = fmaxf(xv[j], 0.f);
        }
#pragma unroll
        for (int j = 0; j < 4; ++j) {
            const int k = kk * 4 + j;
#pragma unroll
            for (int c = 0; c < 3; ++c) {
                acc0[c] = fmaf(xv[j], ws0[k * 3 + c], acc0[c]);
                acc1[c] = fmaf(xv[j], ws1[k * 3 + c], acc1[c]);
            }
        }
    }
    h0[(size_t)r * 3 + 0] = acc0[0];
    h0[(size_t)r * 3 + 1] = acc0[1];
    h0[(size_t)r * 3 + 2] = acc0[2];
    h1[(size_t)r * 3 + 0] = acc1[0];
    h1[(size_t)r * 3 + 1] = acc1[1];
    h1[(size_t)r * 3 + 2] = acc1[2];
}

// ---------------- adjacency build (once per launch) ----------------
// cnt[v] ends as degree(v); adj[v*ADJ_CAP + i] lists neighbors (incl. dup/self edges).
__global__ void build_adj_kernel(const int* __restrict__ edges, int* __restrict__ cnt,
                                 int* __restrict__ adj, int n_edges)
{
    const int e = blockIdx.x * blockDim.x + threadIdx.x;
    if (e >= n_edges) return;
    const int s = edges[2 * e + 0];
    const int d = edges[2 * e + 1];
    int p = atomicAdd(&cnt[s], 1);
    if (p < ADJ_CAP) adj[(size_t)s * ADJ_CAP + p] = d;
    p = atomicAdd(&cnt[d], 1);
    if (p < ADJ_CAP) adj[(size_t)d * ADJ_CAP + p] = s;
}

// ---------------- gather aggregation: h0io[v] += sum_{u in adj[v]} h1[u] ----------------
template<int DOUT>
__global__ void gather_kernel(const int* __restrict__ cnt, const int* __restrict__ adj,
                              const float* __restrict__ h1, float* __restrict__ h0io, int N)
{
    constexpr int TPN = DOUT / 4;             // threads per node, 4 cols each
    const int t = blockIdx.x * blockDim.x + threadIdx.x;
    const int v = t / TPN;
    const int c = (t - v * TPN) * 4;
    if (v >= N) return;

    int deg = cnt[v];
    if (deg > ADJ_CAP) deg = ADJ_CAP;

    float4 acc = *reinterpret_cast<const float4*>(&h0io[(size_t)v * DOUT + c]);
    const int* lst = adj + (size_t)v * ADJ_CAP;
    for (int i = 0; i < deg; ++i) {
        const int u = lst[i];
        const float4 hv = *reinterpret_cast<const float4*>(&h1[(size_t)u * DOUT + c]);
        acc.x += hv.x; acc.y += hv.y; acc.z += hv.z; acc.w += hv.w;
    }
    *reinterpret_cast<float4*>(&h0io[(size_t)v * DOUT + c]) = acc;
}

__global__ void gather3_kernel(const int* __restrict__ cnt, const int* __restrict__ adj,
                               const float* __restrict__ h1, float* __restrict__ h0io, int N)
{
    const int v = blockIdx.x * blockDim.x + threadIdx.x;
    if (v >= N) return;
    int deg = cnt[v];
    if (deg > ADJ_CAP) deg = ADJ_CAP;
    float a0 = h0io[(size_t)v * 3 + 0];
    float a1 = h0io[(size_t)v * 3 + 1];
    float a2 = h0io[(size_t)v * 3 + 2];
    const int* lst = adj + (size_t)v * ADJ_CAP;
    for (int i = 0; i < deg; ++i) {
        const int u = lst[i];
        a0 += h1[(size_t)u * 3 + 0];
        a1 += h1[(size_t)u * 3 + 1];
        a2 += h1[(size_t)u * 3 + 2];
    }
    h0io[(size_t)v * 3 + 0] = a0;
    h0io[(size_t)v * 3 + 1] = a1;
    h0io[(size_t)v * 3 + 2] = a2;
}

extern "C" void kernel_launch(void* const* d_in, const int* in_sizes, int n_in,
                              void* d_out, int out_size, void* d_ws, size_t ws_size,
                              hipStream_t stream)
{
    const float* feat  = (const float*)d_in[0];
    const int*   edges = (const int*)d_in[1];
    const float *W0[4], *B0[4], *W1[4], *B1[4];
    for (int i = 0; i < 4; ++i) {
        W0[i] = (const float*)d_in[2 + i * 4 + 0];
        B0[i] = (const float*)d_in[2 + i * 4 + 1];
        W1[i] = (const float*)d_in[2 + i * 4 + 2];
        B1[i] = (const float*)d_in[2 + i * 4 + 3];
    }
    const int N  = in_sizes[0] / 256;
    const int nE = in_sizes[1] / 2;

    float* out  = (float*)d_out;
    float* bufA = (float*)d_ws;                       // N*192 f32
    float* bufB = bufA + (size_t)N * 192;             // N*192 f32
    float* bufC = bufB + (size_t)N * 192;             // N*128 f32
    int*   cnt  = (int*)(bufC + (size_t)N * 128);     // N int
    int*   adj  = cnt + N;                            // N*ADJ_CAP int
    // ws use ~= 443 MB

    // ---- build adjacency (reused by all 4 layers) ----
    hipMemsetAsync(cnt, 0, (size_t)N * sizeof(int), stream);
    build_adj_kernel<<<(nE + 255) / 256, 256, 0, stream>>>(edges, cnt, adj, nE);

    constexpr int BM = 16;
    const int gGemm = (N + BM - 1) / BM;

    // layer 0: 256 -> 192
    gemm2_kernel<256, 192, BM><<<gGemm, 192, 0, stream>>>(feat, W0[0], B0[0], W1[0], B1[0], bufA, bufB, N, 0);
    gather_kernel<192><<<((size_t)N * 48 + 255) / 256, 256, 0, stream>>>(cnt, adj, bufB, bufA, N);

    // layer 1: 192 -> 128
    gemm2_kernel<192, 128, BM><<<gGemm, 128, 0, stream>>>(bufA, W0[1], B0[1], W1[1], B1[1], bufC, bufB, N, 1);
    gather_kernel<128><<<((size_t)N * 32 + 255) / 256, 256, 0, stream>>>(cnt, adj, bufB, bufC, N);

    // layer 2: 128 -> 64
    gemm2_kernel<128, 64, BM><<<gGemm, 64, 0, stream>>>(bufC, W0[2], B0[2], W1[2], B1[2], bufA, bufB, N, 1);
    gather_kernel<64><<<((size_t)N * 16 + 255) / 256, 256, 0, stream>>>(cnt, adj, bufB, bufA, N);

    // layer 3: 64 -> 3
    gemm2_small_kernel<<<(N + 255) / 256, 256, 0, stream>>>(bufA, W0[3], B0[3], W1[3], B1[3], out, bufB, N, 1);
    gather3_kernel<<<(N + 255) / 256, 256, 0, stream>>>(cnt, adj, bufB, out, N);
}

// Round 5
// 1072.099 us; speedup vs baseline: 2.7901x; 1.8805x over previous
//
#include <hip/hip_runtime.h>
#include <hip/hip_bf16.h>

#define ADJ_CAP 32

typedef __bf16 bf16x8 __attribute__((ext_vector_type(8)));
typedef float  f32x4  __attribute__((ext_vector_type(4)));
typedef unsigned short u16x8 __attribute__((ext_vector_type(8)));

static __device__ __forceinline__ float bf16bits_to_f32(unsigned short u) {
    return __uint_as_float(((unsigned)u) << 16);
}
static __device__ __forceinline__ unsigned short f32_to_bf16bits(float f) {
    __hip_bfloat16 b = __float2bfloat16(f);   // RNE
    return *reinterpret_cast<unsigned short*>(&b);
}

// ---------------- weight pack: w[DIN][DOUT] f32 -> MFMA B-fragment stream bf16 ----------------
// frag (kk,n): lane l, elem j  <-  w[kk*32 + (l>>4)*8 + j][n*16 + (l&15)]
template<int DIN, int DOUT>
__global__ void pack_w_kernel(const float* __restrict__ w, __hip_bfloat16* __restrict__ wp)
{
    constexpr int NS = DOUT / 16;
    const int idx = blockIdx.x * blockDim.x + threadIdx.x;
    if (idx >= DIN * DOUT) return;
    const int j    = idx & 7;
    const int l    = (idx >> 3) & 63;
    const int rest = idx >> 9;
    const int n    = rest % NS;
    const int kk   = rest / NS;
    const int k    = kk * 32 + (l >> 4) * 8 + j;
    const int col  = n * 16 + (l & 15);
    wp[idx] = __float2bfloat16(w[k * DOUT + col]);
}

// ---------------- f32 -> bf16 convert (features), 8 elems/thread ----------------
__global__ void f32_to_bf16_kernel(const float* __restrict__ in, __hip_bfloat16* __restrict__ out, int n8)
{
    const int i = blockIdx.x * blockDim.x + threadIdx.x;
    if (i >= n8) return;
    const float4 a = reinterpret_cast<const float4*>(in)[2 * i + 0];
    const float4 b = reinterpret_cast<const float4*>(in)[2 * i + 1];
    u16x8 o;
    o[0] = f32_to_bf16bits(a.x); o[1] = f32_to_bf16bits(a.y);
    o[2] = f32_to_bf16bits(a.z); o[3] = f32_to_bf16bits(a.w);
    o[4] = f32_to_bf16bits(b.x); o[5] = f32_to_bf16bits(b.y);
    o[6] = f32_to_bf16bits(b.z); o[7] = f32_to_bf16bits(b.w);
    reinterpret_cast<u16x8*>(out)[i] = o;
}

// ---------------- MFMA dual GEMM: h0 = x@w0+b0 (f32), h1 = x@w1+b1 (bf16) ----------------
// block = 256 threads = 4 waves; wave handles 32 rows (2 A-frags), all DOUT cols.
// A loaded global->reg (each x row read exactly once); B from packed fragment stream (L1/L2-hot).
template<int DIN, int DOUT>
__launch_bounds__(256)
__global__ void gemm2_mfma_kernel(const __hip_bfloat16* __restrict__ x,
                                  const __hip_bfloat16* __restrict__ w0p, const float* __restrict__ b0,
                                  const __hip_bfloat16* __restrict__ w1p, const float* __restrict__ b1,
                                  float* __restrict__ h0, __hip_bfloat16* __restrict__ h1, int N)
{
    constexpr int NS = DOUT / 16;
    constexpr int KS = DIN / 32;
    const int wid  = threadIdx.x >> 6;
    const int lane = threadIdx.x & 63;
    const int row0 = blockIdx.x * 128 + wid * 32;   // 32 rows per wave
    if (row0 >= N) return;                           // N % 32 == 0 -> wave-granular guard

    f32x4 acc0[2][NS], acc1[2][NS];
#pragma unroll
    for (int n = 0; n < NS; ++n) {
        const float v0 = b0[n * 16 + (lane & 15)];
        const float v1 = b1[n * 16 + (lane & 15)];
#pragma unroll
        for (int m = 0; m < 2; ++m) {
            acc0[m][n] = f32x4{v0, v0, v0, v0};
            acc1[m][n] = f32x4{v1, v1, v1, v1};
        }
    }

    const bf16x8* xr0 = reinterpret_cast<const bf16x8*>(x + (size_t)(row0 +      (lane & 15)) * DIN);
    const bf16x8* xr1 = reinterpret_cast<const bf16x8*>(x + (size_t)(row0 + 16 + (lane & 15)) * DIN);
    const bf16x8* w0f = reinterpret_cast<const bf16x8*>(w0p);
    const bf16x8* w1f = reinterpret_cast<const bf16x8*>(w1p);
    const int kgrp = (lane >> 4);

#pragma unroll
    for (int kk = 0; kk < KS; ++kk) {
        const bf16x8 a0 = xr0[kk * 4 + kgrp];
        const bf16x8 a1 = xr1[kk * 4 + kgrp];
#pragma unroll
        for (int n = 0; n < NS; ++n) {
            const bf16x8 bv0 = w0f[(kk * NS + n) * 64 + lane];
            const bf16x8 bv1 = w1f[(kk * NS + n) * 64 + lane];
            acc0[0][n] = __builtin_amdgcn_mfma_f32_16x16x32_bf16(a0, bv0, acc0[0][n], 0, 0, 0);
            acc0[1][n] = __builtin_amdgcn_mfma_f32_16x16x32_bf16(a1, bv0, acc0[1][n], 0, 0, 0);
            acc1[0][n] = __builtin_amdgcn_mfma_f32_16x16x32_bf16(a0, bv1, acc1[0][n], 0, 0, 0);
            acc1[1][n] = __builtin_amdgcn_mfma_f32_16x16x32_bf16(a1, bv1, acc1[1][n], 0, 0, 0);
        }
    }

    // C/D layout: col = lane&15, row = (lane>>4)*4 + reg   [m89-verified]
    const int ccol  = lane & 15;
    const int crow0 = (lane >> 4) * 4;
#pragma unroll
    for (int m = 0; m < 2; ++m) {
#pragma unroll
        for (int n = 0; n < NS; ++n) {
#pragma unroll
            for (int r = 0; r < 4; ++r) {
                const int row = row0 + m * 16 + crow0 + r;
                const int col = n * 16 + ccol;
                if (row < N) {
                    h0[(size_t)row * DOUT + col] = acc0[m][n][r];
                    h1[(size_t)row * DOUT + col] = __float2bfloat16(acc1[m][n][r]);
                }
            }
        }
    }
}

// ---------------- layer 3: DIN=64, DOUT=3, bf16 in, f32 out ----------------
__global__ void gemm2_small_kernel(const __hip_bfloat16* __restrict__ x,
                                   const float* __restrict__ w0, const float* __restrict__ b0,
                                   const float* __restrict__ w1, const float* __restrict__ b1,
                                   float* __restrict__ h0, float* __restrict__ h1, int N)
{
    __shared__ float ws0[64 * 3];
    __shared__ float ws1[64 * 3];
    const int tid = threadIdx.x;
    if (tid < 192) { ws0[tid] = w0[tid]; ws1[tid] = w1[tid]; }
    __syncthreads();

    const int r = blockIdx.x * blockDim.x + tid;
    if (r >= N) return;

    float acc0[3] = { b0[0], b0[1], b0[2] };
    float acc1[3] = { b1[0], b1[1], b1[2] };

    const u16x8* x8 = reinterpret_cast<const u16x8*>(x + (size_t)r * 64);
#pragma unroll
    for (int kk = 0; kk < 8; ++kk) {
        const u16x8 v = x8[kk];
#pragma unroll
        for (int j = 0; j < 8; ++j) {
            const float xv = bf16bits_to_f32(v[j]);
            const int k = kk * 8 + j;
#pragma unroll
            for (int c = 0; c < 3; ++c) {
                acc0[c] = fmaf(xv, ws0[k * 3 + c], acc0[c]);
                acc1[c] = fmaf(xv, ws1[k * 3 + c], acc1[c]);
            }
        }
    }
#pragma unroll
    for (int c = 0; c < 3; ++c) {
        h0[(size_t)r * 3 + c] = acc0[c];
        h1[(size_t)r * 3 + c] = acc1[c];
    }
}

// ---------------- adjacency build ----------------
__global__ void build_adj_kernel(const int* __restrict__ edges, int* __restrict__ cnt,
                                 int* __restrict__ adj, int n_edges)
{
    const int e = blockIdx.x * blockDim.x + threadIdx.x;
    if (e >= n_edges) return;
    const int s = edges[2 * e + 0];
    const int d = edges[2 * e + 1];
    int p = atomicAdd(&cnt[s], 1);
    if (p < ADJ_CAP) adj[(size_t)s * ADJ_CAP + p] = d;
    p = atomicAdd(&cnt[d], 1);
    if (p < ADJ_CAP) adj[(size_t)d * ADJ_CAP + p] = s;
}

// ---------------- gather: xout = relu(h0 + sum_{u in adj[v]} h1[u]) -> bf16 ----------------
template<int DOUT>
__global__ void gather_bf16_kernel(const int* __restrict__ cnt, const int* __restrict__ adj,
                                   const __hip_bfloat16* __restrict__ h1, const float* __restrict__ h0,
                                   __hip_bfloat16* __restrict__ xout, int N)
{
    constexpr int TPN = DOUT / 8;                 // 8 cols (16B bf16) per thread
    const int t = blockIdx.x * blockDim.x + threadIdx.x;
    const int v = t / TPN;
    if (v >= N) return;
    const int c = (t - v * TPN) * 8;

    int deg = cnt[v];
    if (deg > ADJ_CAP) deg = ADJ_CAP;

    const float4* h0p = reinterpret_cast<const float4*>(h0 + (size_t)v * DOUT + c);
    const float4 q0 = h0p[0], q1 = h0p[1];
    float a[8] = { q0.x, q0.y, q0.z, q0.w, q1.x, q1.y, q1.z, q1.w };

    const int* lst = adj + (size_t)v * ADJ_CAP;
    for (int i = 0; i < deg; ++i) {
        const int u = lst[i];
        const u16x8 hv = *reinterpret_cast<const u16x8*>(h1 + (size_t)u * DOUT + c);
#pragma unroll
        for (int j = 0; j < 8; ++j) a[j] += bf16bits_to_f32(hv[j]);
    }

    u16x8 o;
#pragma unroll
    for (int j = 0; j < 8; ++j) o[j] = f32_to_bf16bits(fmaxf(a[j], 0.f));
    *reinterpret_cast<u16x8*>(xout + (size_t)v * DOUT + c) = o;
}

// layer 3 gather: f32, no relu, in-place on out
__global__ void gather3_kernel(const int* __restrict__ cnt, const int* __restrict__ adj,
                               const float* __restrict__ h1, float* __restrict__ h0io, int N)
{
    const int v = blockIdx.x * blockDim.x + threadIdx.x;
    if (v >= N) return;
    int deg = cnt[v];
    if (deg > ADJ_CAP) deg = ADJ_CAP;
    float a0 = h0io[(size_t)v * 3 + 0];
    float a1 = h0io[(size_t)v * 3 + 1];
    float a2 = h0io[(size_t)v * 3 + 2];
    const int* lst = adj + (size_t)v * ADJ_CAP;
    for (int i = 0; i < deg; ++i) {
        const int u = lst[i];
        a0 += h1[(size_t)u * 3 + 0];
        a1 += h1[(size_t)u * 3 + 1];
        a2 += h1[(size_t)u * 3 + 2];
    }
    h0io[(size_t)v * 3 + 0] = a0;
    h0io[(size_t)v * 3 + 1] = a1;
    h0io[(size_t)v * 3 + 2] = a2;
}

extern "C" void kernel_launch(void* const* d_in, const int* in_sizes, int n_in,
                              void* d_out, int out_size, void* d_ws, size_t ws_size,
                              hipStream_t stream)
{
    const float* feat  = (const float*)d_in[0];
    const int*   edges = (const int*)d_in[1];
    const float *W0[4], *B0[4], *W1[4], *B1[4];
    for (int i = 0; i < 4; ++i) {
        W0[i] = (const float*)d_in[2 + i * 4 + 0];
        B0[i] = (const float*)d_in[2 + i * 4 + 1];
        W1[i] = (const float*)d_in[2 + i * 4 + 2];
        B1[i] = (const float*)d_in[2 + i * 4 + 3];
    }
    const int N  = in_sizes[0] / 256;
    const int nE = in_sizes[1] / 2;

    float* out = (float*)d_out;

    // ---- workspace layout (~439 MB) ----
    char* p = (char*)d_ws;
    float*          h0   = (float*)p;            p += (size_t)N * 192 * sizeof(float);
    __hip_bfloat16* h1b  = (__hip_bfloat16*)p;   p += (size_t)N * 192 * sizeof(__hip_bfloat16);
    __hip_bfloat16* xA   = (__hip_bfloat16*)p;   p += (size_t)N * 256 * sizeof(__hip_bfloat16);
    __hip_bfloat16* xB   = (__hip_bfloat16*)p;   p += (size_t)N * 192 * sizeof(__hip_bfloat16);
    float*          h1s  = (float*)p;            p += (size_t)N * 3 * sizeof(float);
    int*            cnt  = (int*)p;              p += (size_t)N * sizeof(int);
    int*            adj  = (int*)p;              p += (size_t)N * ADJ_CAP * sizeof(int);
    __hip_bfloat16* wp00 = (__hip_bfloat16*)p;   p += 256 * 192 * sizeof(__hip_bfloat16);
    __hip_bfloat16* wp01 = (__hip_bfloat16*)p;   p += 256 * 192 * sizeof(__hip_bfloat16);
    __hip_bfloat16* wp10 = (__hip_bfloat16*)p;   p += 192 * 128 * sizeof(__hip_bfloat16);
    __hip_bfloat16* wp11 = (__hip_bfloat16*)p;   p += 192 * 128 * sizeof(__hip_bfloat16);
    __hip_bfloat16* wp20 = (__hip_bfloat16*)p;   p += 128 * 64 * sizeof(__hip_bfloat16);
    __hip_bfloat16* wp21 = (__hip_bfloat16*)p;   p += 128 * 64 * sizeof(__hip_bfloat16);

    // ---- adjacency (reused by all layers) ----
    hipMemsetAsync(cnt, 0, (size_t)N * sizeof(int), stream);
    build_adj_kernel<<<(nE + 255) / 256, 256, 0, stream>>>(edges, cnt, adj, nE);

    // ---- weight packing ----
    pack_w_kernel<256, 192><<<(256 * 192 + 255) / 256, 256, 0, stream>>>(W0[0], wp00);
    pack_w_kernel<256, 192><<<(256 * 192 + 255) / 256, 256, 0, stream>>>(W1[0], wp01);
    pack_w_kernel<192, 128><<<(192 * 128 + 255) / 256, 256, 0, stream>>>(W0[1], wp10);
    pack_w_kernel<192, 128><<<(192 * 128 + 255) / 256, 256, 0, stream>>>(W1[1], wp11);
    pack_w_kernel<128, 64><<<(128 * 64 + 255) / 256, 256, 0, stream>>>(W0[2], wp20);
    pack_w_kernel<128, 64><<<(128 * 64 + 255) / 256, 256, 0, stream>>>(W1[2], wp21);

    // ---- features f32 -> bf16 ----
    f32_to_bf16_kernel<<<((N * 256 / 8) + 255) / 256, 256, 0, stream>>>(feat, xA, N * 256 / 8);

    const int gGemm = (N + 127) / 128;

    // layer 0: 256 -> 192
    gemm2_mfma_kernel<256, 192><<<gGemm, 256, 0, stream>>>(xA, wp00, B0[0], wp01, B1[0], h0, h1b, N);
    gather_bf16_kernel<192><<<((size_t)N * 24 + 255) / 256, 256, 0, stream>>>(cnt, adj, h1b, h0, xB, N);

    // layer 1: 192 -> 128
    gemm2_mfma_kernel<192, 128><<<gGemm, 256, 0, stream>>>(xB, wp10, B0[1], wp11, B1[1], h0, h1b, N);
    gather_bf16_kernel<128><<<((size_t)N * 16 + 255) / 256, 256, 0, stream>>>(cnt, adj, h1b, h0, xA, N);

    // layer 2: 128 -> 64
    gemm2_mfma_kernel<128, 64><<<gGemm, 256, 0, stream>>>(xA, wp20, B0[2], wp21, B1[2], h0, h1b, N);
    gather_bf16_kernel<64><<<((size_t)N * 8 + 255) / 256, 256, 0, stream>>>(cnt, adj, h1b, h0, xB, N);

    // layer 3: 64 -> 3
    gemm2_small_kernel<<<(N + 255) / 256, 256, 0, stream>>>(xB, W0[3], B0[3], W1[3], B1[3], out, h1s, N);
    gather3_kernel<<<(N + 255) / 256, 256, 0, stream>>>(cnt, adj, h1s, out, N);
}